// Round 9
// baseline (246.694 us; speedup 1.0000x reference)
//
#include <hip/hip_runtime.h>

typedef unsigned short u16;
typedef unsigned int   u32;

typedef short s16x8 __attribute__((ext_vector_type(8)));
typedef float f32x4 __attribute__((ext_vector_type(4)));

static __device__ __forceinline__ u16 f2bf(float f) {
  u32 u = __float_as_uint(f);
  u = (u + 0x7fffu + ((u >> 16) & 1u)) >> 16;
  return (u16)u;
}
static __device__ __forceinline__ float bf2f(u16 h) {
  return __uint_as_float(((u32)h) << 16);
}
static __device__ __forceinline__ f32x4 mfma16(s16x8 a, s16x8 b, f32x4 c) {
  return __builtin_amdgcn_mfma_f32_16x16x32_bf16(a, b, c, 0, 0, 0);
}
static __device__ __forceinline__ void gload16(const u16* g, u16* l) {
  __builtin_amdgcn_global_load_lds(
      (const __attribute__((address_space(1))) void*)g,
      (__attribute__((address_space(3))) void*)l, 16, 0, 0);
}

#define WAITVM8() asm volatile("s_waitcnt vmcnt(8)" ::: "memory")
#define WAITVM4() asm volatile("s_waitcnt vmcnt(4)" ::: "memory")
#define WAITVM2() asm volatile("s_waitcnt vmcnt(2)" ::: "memory")
#define WAITVM0() asm volatile("s_waitcnt vmcnt(0)" ::: "memory")
#define BAR()                                  \
  do {                                         \
    asm volatile("" ::: "memory");             \
    __builtin_amdgcn_s_barrier();              \
    asm volatile("" ::: "memory");             \
  } while (0)

// ---------------- flat f32 -> bf16 convert, 8 elems/thread ----------------
__global__ __launch_bounds__(256) void cvt_k(const float* __restrict__ in,
                                             u16* __restrict__ out, int n8) {
  int i = blockIdx.x * 256 + threadIdx.x;
  if (i >= n8) return;
  const float4* p = reinterpret_cast<const float4*>(in);
  float4 a = p[2 * i], b = p[2 * i + 1];
  union { u16 u[8]; uint4 v; } r;
  r.u[0] = f2bf(a.x); r.u[1] = f2bf(a.y); r.u[2] = f2bf(a.z); r.u[3] = f2bf(a.w);
  r.u[4] = f2bf(b.x); r.u[5] = f2bf(b.y); r.u[6] = f2bf(b.z); r.u[7] = f2bf(b.w);
  reinterpret_cast<uint4*>(out)[i] = r.v;
}

// ------------- transpose+convert: in [R,C] f32 -> out [C,R] bf16, batched -------------
__global__ void tcvt_k(const float* __restrict__ in, u16* __restrict__ out,
                       int R, int C, long long ibs, long long obs) {
  __shared__ float t[32][33];
  const float* ip = in + (size_t)blockIdx.z * ibs;
  u16* op = out + (size_t)blockIdx.z * obs;
  int r0 = blockIdx.y * 32, c0 = blockIdx.x * 32;
  int x = threadIdx.x, y = threadIdx.y;
  for (int i = y; i < 32; i += 8) t[i][x] = ip[(size_t)(r0 + i) * C + c0 + x];
  __syncthreads();
  for (int i = y; i < 32; i += 8) op[(size_t)(c0 + i) * R + r0 + x] = f2bf(t[x][i]);
}

// ------------- row softmax with mask, bf16 in-place (dense stride 2048) -------------
__global__ __launch_bounds__(256) void softmax_k(u16* __restrict__ P,
                                                 const int* __restrict__ mask,
                                                 float scale) {
  __shared__ float redm[4], reds[4];
  const int row = blockIdx.x;
  const int bb = row >> 11;
  const int tid = threadIdx.x;
  u16* p = P + (size_t)row * 2048;
  const int* mk = mask + (size_t)bb * 2048;
  uint4 raw = reinterpret_cast<const uint4*>(p)[tid];
  int4 ma = reinterpret_cast<const int4*>(mk)[2 * tid];
  int4 mc = reinterpret_cast<const int4*>(mk)[2 * tid + 1];
  float v[8];
  v[0] = ma.x ? bf2f((u16)(raw.x & 0xffff)) * scale : -1e30f;
  v[1] = ma.y ? bf2f((u16)(raw.x >> 16))    * scale : -1e30f;
  v[2] = ma.z ? bf2f((u16)(raw.y & 0xffff)) * scale : -1e30f;
  v[3] = ma.w ? bf2f((u16)(raw.y >> 16))    * scale : -1e30f;
  v[4] = mc.x ? bf2f((u16)(raw.z & 0xffff)) * scale : -1e30f;
  v[5] = mc.y ? bf2f((u16)(raw.z >> 16))    * scale : -1e30f;
  v[6] = mc.z ? bf2f((u16)(raw.w & 0xffff)) * scale : -1e30f;
  v[7] = mc.w ? bf2f((u16)(raw.w >> 16))    * scale : -1e30f;
  float mx = v[0];
  #pragma unroll
  for (int i = 1; i < 8; ++i) mx = fmaxf(mx, v[i]);
  for (int off = 32; off; off >>= 1) mx = fmaxf(mx, __shfl_xor(mx, off));
  if ((tid & 63) == 0) redm[tid >> 6] = mx;
  __syncthreads();
  mx = fmaxf(fmaxf(redm[0], redm[1]), fmaxf(redm[2], redm[3]));
  float sum = 0.f;
  #pragma unroll
  for (int i = 0; i < 8; ++i) { v[i] = __expf(v[i] - mx); sum += v[i]; }
  for (int off = 32; off; off >>= 1) sum += __shfl_xor(sum, off);
  if ((tid & 63) == 0) reds[tid >> 6] = sum;
  __syncthreads();
  sum = reds[0] + reds[1] + reds[2] + reds[3];
  float inv = 1.0f / sum;
  union { u16 u[8]; uint4 q; } r;
  #pragma unroll
  for (int i = 0; i < 8; ++i) r.u[i] = f2bf(v[i] * inv);
  reinterpret_cast<uint4*>(p)[tid] = r.q;
}

// ======== 256x256 / BK=64, 8-wave, 4-phase-per-tile deep-pipelined GEMM ========
// Per tile: 4 phases {ds_read quad | stage 2 rounds of next tile | BAR | 16 MFMA | BAR}.
// Stage order B01,B23,A02,A13 gives every region >=2-phase lead; counted vmcnt(4)@ph1,
// vmcnt(2)@ph3 (never 0 in steady state). T2 swizzle; XCD-chunked grid; LDS epilogue.
// NOTE: LDS buffer bases computed at runtime (SM + buf*16384) — an array of pointers
// into __shared__ miscompiles on gfx950 (addrspacecast in static initializer).
template <int EPI, int NT, int NX, int NY, int LDA, int LDB, int LDC,
          int KSPLIT, int MSPLIT, long long ABS, long long BBS, long long CBS,
          int NWG>
__global__ __launch_bounds__(512) void g256(
    const u16* __restrict__ A, const u16* __restrict__ A2,
    const u16* __restrict__ Bt, const u16* __restrict__ Bt2,
    float* __restrict__ Cf, u16* __restrict__ Cb,
    const float* __restrict__ R0, const u16* __restrict__ R1) {
  __shared__ u16 SM[65536];                       // 128 KB
  const int bid = blockIdx.x;
  const int wgid = (bid & 7) * (NWG / 8) + (bid >> 3);
  const int bx = wgid % NX;
  const int by = (wgid / NX) % NY;
  const int bz = wgid / (NX * NY);
  const int tid = threadIdx.x;
  const int wave = tid >> 6, lane = tid & 63;
  const int m0 = by * 256, n0 = bx * 256;
  const int wr = wave >> 2, wc = wave & 3;        // 2x4 waves, each 128x64 of C
  const int l15 = lane & 15, l4 = lane >> 4;
  const int scolsw = (((tid & 7) ^ ((tid >> 3) & 7)) << 3);  // pre-swizzled src col
  const u16* Bbase = ((m0 < MSPLIT) ? Bt : Bt2) + (size_t)bz * BBS;
  const u16* Ab0 = A + (size_t)bz * ABS;
  const u16* Ab1 = A2 + (size_t)bz * ABS;

  f32x4 acc[8][4];
  #pragma unroll
  for (int i = 0; i < 8; ++i)
    #pragma unroll
    for (int j = 0; j < 4; ++j) acc[i][j] = (f32x4){0.f, 0.f, 0.f, 0.f};

  // runtime LDS base computation (A: buf*16384, B: 32768 + buf*16384, u16 units)
  auto ASb = [&](int buf) -> u16* { return SM + buf * 16384; };
  auto BSb = [&](int buf) -> u16* { return SM + 32768 + buf * 16384; };

  // stage round r (64 rows x 64 cols = 8KB, 1 gload/thread)
  auto stA = [&](int buf, int k0, int r) {
    const u16* Ab; int kl;
    if (k0 < KSPLIT) { Ab = Ab0; kl = k0; } else { Ab = Ab1; kl = k0 - KSPLIT; }
    gload16(Ab + (size_t)(m0 + r * 64 + (tid >> 3)) * LDA + kl + scolsw,
            ASb(buf) + r * 4096 + tid * 8);
  };
  auto stB = [&](int buf, int k0, int r) {
    gload16(Bbase + (size_t)(n0 + r * 64 + (tid >> 3)) * LDB + k0 + scolsw,
            BSb(buf) + r * 4096 + tid * 8);
  };
  // fragment read: row-major [256][64], slot XOR (row&7)
  auto ldf = [&](const u16* base, int row, int kq) {
    int slot = (kq * 4 + l4) ^ (row & 7);
    return *reinterpret_cast<const s16x8*>(base + row * 64 + slot * 8);
  };

  // prologue: tile 0 fully resident
  #pragma unroll
  for (int r = 0; r < 4; ++r) stB(0, 0, r);
  #pragma unroll
  for (int r = 0; r < 4; ++r) stA(0, 0, r);
  WAITVM0();
  BAR();

  for (int t = 0; t < NT; ++t) {
    const int c = t & 1;
    const int nk = (t + 1) * 64;
    const bool st = (t + 1 < NT);
    s16x8 bfr[4][2], af[4];

    // ---- phase 0: h=0,k=0; B frags (both k) + A quad; stage B rows 0-127 ----
    #pragma unroll
    for (int ni = 0; ni < 4; ++ni)
      #pragma unroll
      for (int kq = 0; kq < 2; ++kq)
        bfr[ni][kq] = ldf(BSb(c), wc * 64 + ni * 16 + l15, kq);
    #pragma unroll
    for (int mi = 0; mi < 4; ++mi)
      af[mi] = ldf(ASb(c), wr * 128 + mi * 16 + l15, 0);
    if (st) { stB(c ^ 1, nk, 0); stB(c ^ 1, nk, 1); }
    BAR();
    __builtin_amdgcn_s_setprio(1);
    #pragma unroll
    for (int mi = 0; mi < 4; ++mi)
      #pragma unroll
      for (int ni = 0; ni < 4; ++ni)
        acc[mi][ni] = mfma16(af[mi], bfr[ni][0], acc[mi][ni]);
    __builtin_amdgcn_s_setprio(0);
    BAR();

    // ---- phase 1: h=0,k=1; stage B rows 128-255; vmcnt(4) retires A13(t) ----
    #pragma unroll
    for (int mi = 0; mi < 4; ++mi)
      af[mi] = ldf(ASb(c), wr * 128 + mi * 16 + l15, 1);
    if (st) { stB(c ^ 1, nk, 2); stB(c ^ 1, nk, 3); }
    BAR();
    __builtin_amdgcn_s_setprio(1);
    #pragma unroll
    for (int mi = 0; mi < 4; ++mi)
      #pragma unroll
      for (int ni = 0; ni < 4; ++ni)
        acc[mi][ni] = mfma16(af[mi], bfr[ni][1], acc[mi][ni]);
    __builtin_amdgcn_s_setprio(0);
    if (st) { WAITVM4(); } else { WAITVM0(); }
    BAR();

    // ---- phase 2: h=1,k=0; stage A bands 0,2 ----
    #pragma unroll
    for (int mi = 0; mi < 4; ++mi)
      af[mi] = ldf(ASb(c), wr * 128 + 64 + mi * 16 + l15, 0);
    if (st) { stA(c ^ 1, nk, 0); stA(c ^ 1, nk, 2); }
    BAR();
    __builtin_amdgcn_s_setprio(1);
    #pragma unroll
    for (int mi = 0; mi < 4; ++mi)
      #pragma unroll
      for (int ni = 0; ni < 4; ++ni)
        acc[4 + mi][ni] = mfma16(af[mi], bfr[ni][0], acc[4 + mi][ni]);
    __builtin_amdgcn_s_setprio(0);
    BAR();

    // ---- phase 3: h=1,k=1; stage A bands 1,3; vmcnt(2) retires B+A02(t+1) ----
    #pragma unroll
    for (int mi = 0; mi < 4; ++mi)
      af[mi] = ldf(ASb(c), wr * 128 + 64 + mi * 16 + l15, 1);
    if (st) { stA(c ^ 1, nk, 1); stA(c ^ 1, nk, 3); }
    BAR();
    __builtin_amdgcn_s_setprio(1);
    #pragma unroll
    for (int mi = 0; mi < 4; ++mi)
      #pragma unroll
      for (int ni = 0; ni < 4; ++ni)
        acc[4 + mi][ni] = mfma16(af[mi], bfr[ni][1], acc[4 + mi][ni]);
    __builtin_amdgcn_s_setprio(0);
    if (st) { WAITVM2(); } else { WAITVM0(); }
    BAR();
  }

  // ---- epilogue: 4 chunks of 64 rows x 256 cols f32 through LDS ----
  float* LF = (float*)SM;                       // stride 260 f32, 66.5 KB
  #pragma unroll
  for (int ci = 0; ci < 4; ++ci) {
    __syncthreads();
    #pragma unroll
    for (int u = 0; u < 2; ++u) {
      #pragma unroll
      for (int ni = 0; ni < 4; ++ni) {
        int lr = wr * 32 + u * 16 + l4 * 4;
        int lc = wc * 64 + ni * 16 + l15;
        #pragma unroll
        for (int j = 0; j < 4; ++j)
          LF[(lr + j) * 260 + lc] = acc[2 * ci + u][ni][j];
      }
    }
    __syncthreads();
    int r = tid >> 3;                           // 0..63
    int cb = (tid & 7) * 32;
    int b = r >> 5, sub = r & 31;
    int mf = 2 * ci + (sub >> 4);
    int grow = m0 + b * 128 + (mf >> 2) * 64 + (mf & 3) * 16 + (sub & 15);
    int gcol = n0 + cb;
    float v[32];
    #pragma unroll
    for (int i = 0; i < 8; ++i)
      *reinterpret_cast<f32x4*>(&v[4 * i]) =
          *reinterpret_cast<const f32x4*>(&LF[r * 260 + cb + 4 * i]);
    if (EPI == 3) {
      float* o = Cf + (size_t)bz * CBS + (size_t)grow * LDC + gcol;
      if (n0 < 512) {
        const float* r0 = R0 + (size_t)grow * 512 + gcol;
        #pragma unroll
        for (int i = 0; i < 32; ++i) {
          float g = 1.0f / (1.0f + __expf(-v[i]));
          v[i] = r0[i] * g;
        }
      } else {
        const u16* r1 = R1 + (size_t)grow * 512 + (gcol - 512);
        #pragma unroll
        for (int i = 0; i < 32; ++i) {
          float g = 1.0f / (1.0f + __expf(-v[i]));
          v[i] = bf2f(r1[i]) * g;
        }
      }
      #pragma unroll
      for (int i = 0; i < 8; ++i)
        reinterpret_cast<float4*>(o)[i] = *reinterpret_cast<float4*>(&v[4 * i]);
    } else {
      union { u16 u[32]; uint4 q[4]; } pk;
      #pragma unroll
      for (int i = 0; i < 32; ++i)
        pk.u[i] = f2bf(EPI == 0 ? fmaxf(v[i], 0.f) : v[i]);
      u16* o = Cb + (size_t)bz * CBS + (size_t)grow * LDC + gcol;
      #pragma unroll
      for (int i = 0; i < 4; ++i) reinterpret_cast<uint4*>(o)[i] = pk.q[i];
    }
  }
}

// ======== P @ memory, 128x128 dbuf counted-vmcnt (control, frozen from R7) ========
template <int EPI, int NT, int NX, int NY,
          int LDA, int LDB, int LDC, int KSPLIT, int MSPLIT,
          long long ABS, long long BBS, long long CBS, int NWG>
__global__ __launch_bounds__(256, 2) void gdb(
    const u16* __restrict__ A, const u16* __restrict__ A2,
    const u16* __restrict__ Bt, const u16* __restrict__ Bt2,
    float* __restrict__ Cf, u16* __restrict__ Cb,
    const float* __restrict__ R0, const u16* __restrict__ R1) {
  __shared__ u16 As[2][128 * 64];
  __shared__ u16 Bs[2][128 * 64];
  const int bid = blockIdx.x;
  const int wgid = (bid & 7) * (NWG / 8) + (bid >> 3);
  const int bx = wgid % NX;
  const int by = (wgid / NX) % NY;
  const int bz = wgid / (NX * NY);
  const int tid = threadIdx.x;
  const int wave = tid >> 6, lane = tid & 63;
  const int m0 = by * 128, n0 = bx * 128;
  const int wr = wave >> 1, wc = wave & 1;
  const int l15 = lane & 15, l4 = lane >> 4;
  const int srow = lane >> 3;
  const int scolsw = (((lane & 7) ^ (lane >> 3)) << 3);
  const int rsw = (l15 & 7) << 3;
  const u16* Bbase = ((m0 < MSPLIT) ? Bt : Bt2) + (size_t)bz * BBS;
  const u16* Abase0 = A + (size_t)bz * ABS;
  const u16* Abase1 = A2 + (size_t)bz * ABS;

  f32x4 acc[4][4];
  #pragma unroll
  for (int i = 0; i < 4; ++i)
    #pragma unroll
    for (int j = 0; j < 4; ++j) acc[i][j] = (f32x4){0.f, 0.f, 0.f, 0.f};

  auto stage = [&](int buf, int k0) {
    const u16* Ab;
    int kl;
    if (k0 < KSPLIT) { Ab = Abase0; kl = k0; }
    else             { Ab = Abase1; kl = k0 - KSPLIT; }
    #pragma unroll
    for (int c = 0; c < 4; ++c) {
      int chunk = wave * 4 + c;
      int row = chunk * 8 + srow;
      gload16(Ab + (size_t)(m0 + row) * LDA + kl + scolsw, &As[buf][chunk * 512]);
      gload16(Bbase + (size_t)(n0 + row) * LDB + k0 + scolsw, &Bs[buf][chunk * 512]);
    }
  };
  auto compute = [&](int cur) {
    __builtin_amdgcn_s_setprio(1);
    #pragma unroll
    for (int kk = 0; kk < 64; kk += 32) {
      s16x8 af[4], bfr[4];
      #pragma unroll
      for (int mi = 0; mi < 4; ++mi)
        af[mi] = *reinterpret_cast<const s16x8*>(
            &As[cur][(wr * 64 + mi * 16 + l15) * 64 + ((kk + l4 * 8) ^ rsw)]);
      #pragma unroll
      for (int ni = 0; ni < 4; ++ni)
        bfr[ni] = *reinterpret_cast<const s16x8*>(
            &Bs[cur][(wc * 64 + ni * 16 + l15) * 64 + ((kk + l4 * 8) ^ rsw)]);
      #pragma unroll
      for (int mi = 0; mi < 4; ++mi)
        #pragma unroll
        for (int ni = 0; ni < 4; ++ni)
          acc[mi][ni] = mfma16(af[mi], bfr[ni], acc[mi][ni]);
    }
    __builtin_amdgcn_s_setprio(0);
  };

  stage(0, 0);
  stage(1, 64);
  WAITVM8();
  BAR();
  for (int t = 0; t < NT; ++t) {
    const int cur = t & 1;
    compute(cur);
    BAR();
    if (t + 2 < NT) stage(cur, (t + 2) * 64);
    if (t + 1 < NT) {
      if (t + 2 < NT) { WAITVM8(); } else { WAITVM0(); }
      BAR();
    }
  }

  float* LF = (float*)(&As[0][0]);
  const int er = tid >> 3;
  const int ec = (tid & 7) * 16;
  #pragma unroll
  for (int mi = 0; mi < 4; ++mi) {
    __syncthreads();
    #pragma unroll
    for (int ni = 0; ni < 4; ++ni) {
      int lcol = wc * 64 + ni * 16 + l15;
      #pragma unroll
      for (int j = 0; j < 4; ++j)
        LF[(wr * 16 + l4 * 4 + j) * 132 + lcol] = acc[mi][ni][j];
    }
    __syncthreads();
    int grow = m0 + mi * 16 + (er & 15) + (er >> 4) * 64;
    int gcol = n0 + ec;
    float v[16];
    #pragma unroll
    for (int i = 0; i < 4; ++i)
      *reinterpret_cast<f32x4*>(&v[4 * i]) =
          *reinterpret_cast<const f32x4*>(&LF[er * 132 + ec + 4 * i]);
    union { u16 u[16]; uint4 q[2]; } pk;
    #pragma unroll
    for (int i = 0; i < 16; ++i)
      pk.u[i] = f2bf(EPI == 0 ? fmaxf(v[i], 0.f) : v[i]);
    u16* o = Cb + (size_t)bz * CBS + (size_t)grow * LDC + gcol;
    reinterpret_cast<uint4*>(o)[0] = pk.q[0];
    reinterpret_cast<uint4*>(o)[1] = pk.q[1];
  }
  (void)Cf; (void)R0; (void)R1;
}

extern "C" void kernel_launch(void* const* d_in, const int* in_sizes, int n_in,
                              void* d_out, int out_size, void* d_ws, size_t ws_size,
                              hipStream_t stream) {
  const float* inputs = (const float*)d_in[0];  // [8,2048,512]
  const float* memory = (const float*)d_in[1];  // [8,2048,512]
  const int*   mask   = (const int*)d_in[2];    // [8,2048]
  const float* Wq     = (const float*)d_in[3];  // [512,512]
  const float* Wk     = (const float*)d_in[4];  // [512,512]
  const float* Wg     = (const float*)d_in[5];  // [1024,1024]
  float* out = (float*)d_out;                   // [8,2048,1024]

  char* ws = (char*)d_ws;
  size_t off = 0;
  auto alloc = [&](size_t bytes) {
    void* p = ws + off;
    off += (bytes + 255) & ~(size_t)255;
    return p;
  };
  u16* in_b  = (u16*)alloc(16384ULL * 512 * 2);   // } contiguous pair [inputs|memory]
  u16* mem_b = (u16*)alloc(16384ULL * 512 * 2);   // }
  u16* memT  = (u16*)alloc(16384ULL * 512 * 2);   // memory^T bf16 [B][512][2048]
  u16* WqT   = (u16*)alloc(512ULL * 512 * 2);
  u16* WkT   = (u16*)alloc(512ULL * 512 * 2);
  u16* WgT   = (u16*)alloc(1024ULL * 1024 * 2);
  u16* q_b   = (u16*)alloc(16384ULL * 512 * 2);   // } contiguous pair [q|k]
  u16* k_b   = (u16*)alloc(16384ULL * 512 * 2);   // }
  u16* sc    = (u16*)alloc(8ULL * 2048 * 2048 * 2);  // scores/P bf16 dense
  u16* att_b = (u16*)alloc(16384ULL * 512 * 2);
  (void)ws_size; (void)in_sizes; (void)n_in; (void)out_size; (void)mem_b;

  const int n8 = (16384 * 512) / 8;
  cvt_k<<<(n8 + 255) / 256, 256, 0, stream>>>(inputs, in_b, n8);
  cvt_k<<<(n8 + 255) / 256, 256, 0, stream>>>(memory, in_b + 16384ULL * 512, n8);
  dim3 tb(32, 8);
  tcvt_k<<<dim3(16, 16, 1), tb, 0, stream>>>(Wq, WqT, 512, 512, 0, 0);
  tcvt_k<<<dim3(16, 16, 1), tb, 0, stream>>>(Wk, WkT, 512, 512, 0, 0);
  tcvt_k<<<dim3(32, 32, 1), tb, 0, stream>>>(Wg, WgT, 1024, 1024, 0, 0);
  tcvt_k<<<dim3(16, 64, 8), tb, 0, stream>>>(memory, memT, 2048, 512,
                                             2048LL * 512, 2048LL * 512);

  // [q|k] = relu([inputs|memory] @ [Wq or Wk])  M=32768 N=512 K=512, 256 blocks
  g256<0, 8, 2, 128, 512, 512, 512, (1 << 30), 16384, 0, 0, 0, 256>
      <<<256, 512, 0, stream>>>(in_b, in_b, WqT, WkT, nullptr, q_b,
                                nullptr, nullptr);

  // scores[b] = q[b] @ k[b]^T -> bf16 dense [2048][2048], 512 blocks
  g256<1, 8, 8, 8, 512, 512, 2048, (1 << 30), (1 << 30),
       2048LL * 512, 2048LL * 512, 2048LL * 2048, 512>
      <<<512, 512, 0, stream>>>(q_b, q_b, k_b, k_b, nullptr, sc,
                                nullptr, nullptr);

  // masked scaled softmax, bf16 in place (dense)
  softmax_k<<<16384, 256, 0, stream>>>(sc, mask, 0.044194173824159216f);

  // att[b] = P[b] @ memory[b] -> bf16  (M=2048 N=512 K=2048 per batch)
  gdb<1, 32, 4, 16, 2048, 2048, 512, (1 << 30), (1 << 30),
      2048LL * 2048, 512LL * 2048, 2048LL * 512, 512>
      <<<512, 256, 0, stream>>>(sc, sc, memT, memT, nullptr, att_b,
                                nullptr, nullptr);

  // out = res * sigmoid(res @ Wg), res = [inputs | att]; A K-split at 512
  g256<3, 16, 4, 64, 512, 1024, 1024, 512, (1 << 30), 0, 0, 0, 256>
      <<<256, 512, 0, stream>>>(in_b, att_b, WgT, WgT, out, nullptr,
                                inputs, att_b);
}

// Round 10
// 234.673 us; speedup vs baseline: 1.0512x; 1.0512x over previous
//
#include <hip/hip_runtime.h>

typedef unsigned short u16;
typedef unsigned int   u32;

typedef short s16x8 __attribute__((ext_vector_type(8)));
typedef float f32x4 __attribute__((ext_vector_type(4)));

static __device__ __forceinline__ u16 f2bf(float f) {
  u32 u = __float_as_uint(f);
  u = (u + 0x7fffu + ((u >> 16) & 1u)) >> 16;
  return (u16)u;
}
static __device__ __forceinline__ float bf2f(u16 h) {
  return __uint_as_float(((u32)h) << 16);
}
static __device__ __forceinline__ f32x4 mfma16(s16x8 a, s16x8 b, f32x4 c) {
  return __builtin_amdgcn_mfma_f32_16x16x32_bf16(a, b, c, 0, 0, 0);
}
static __device__ __forceinline__ void gload16(const u16* g, u16* l) {
  __builtin_amdgcn_global_load_lds(
      (const __attribute__((address_space(1))) void*)g,
      (__attribute__((address_space(3))) void*)l, 16, 0, 0);
}

#define WAITVM8() asm volatile("s_waitcnt vmcnt(8)" ::: "memory")
#define WAITVM6() asm volatile("s_waitcnt vmcnt(6)" ::: "memory")
#define WAITVM0() asm volatile("s_waitcnt vmcnt(0)" ::: "memory")
#define BAR()                                  \
  do {                                         \
    asm volatile("" ::: "memory");             \
    __builtin_amdgcn_s_barrier();              \
    asm volatile("" ::: "memory");             \
  } while (0)

// ---------------- flat f32 -> bf16 convert, 8 elems/thread ----------------
__global__ __launch_bounds__(256) void cvt_k(const float* __restrict__ in,
                                             u16* __restrict__ out, int n8) {
  int i = blockIdx.x * 256 + threadIdx.x;
  if (i >= n8) return;
  const float4* p = reinterpret_cast<const float4*>(in);
  float4 a = p[2 * i], b = p[2 * i + 1];
  union { u16 u[8]; uint4 v; } r;
  r.u[0] = f2bf(a.x); r.u[1] = f2bf(a.y); r.u[2] = f2bf(a.z); r.u[3] = f2bf(a.w);
  r.u[4] = f2bf(b.x); r.u[5] = f2bf(b.y); r.u[6] = f2bf(b.z); r.u[7] = f2bf(b.w);
  reinterpret_cast<uint4*>(out)[i] = r.v;
}

// ------- memory: one read -> bf16 row-major copy AND bf16 transpose -------
// in [8][2048][512] f32 -> rm [8][2048][512] bf16, tr [8][512][2048] bf16
__global__ void cvtT_k(const float* __restrict__ in, u16* __restrict__ rm,
                       u16* __restrict__ tr) {
  __shared__ float t[32][33];
  const int z = blockIdx.z;
  const float* ip = in + (size_t)z * 2048 * 512;
  int r0 = blockIdx.y * 32, c0 = blockIdx.x * 32;
  int x = threadIdx.x, y = threadIdx.y;
  for (int i = y; i < 32; i += 8) t[i][x] = ip[(size_t)(r0 + i) * 512 + c0 + x];
  __syncthreads();
  u16* rp = rm + (size_t)z * 2048 * 512;
  u16* tp = tr + (size_t)z * 512 * 2048;
  for (int i = y; i < 32; i += 8) rp[(size_t)(r0 + i) * 512 + c0 + x] = f2bf(t[i][x]);
  for (int i = y; i < 32; i += 8) tp[(size_t)(c0 + i) * 2048 + r0 + x] = f2bf(t[x][i]);
}

// ------------- transpose+convert: in [R,C] f32 -> out [C,R] bf16 -------------
__global__ void tcvt_k(const float* __restrict__ in, u16* __restrict__ out,
                       int R, int C, long long ibs, long long obs) {
  __shared__ float t[32][33];
  const float* ip = in + (size_t)blockIdx.z * ibs;
  u16* op = out + (size_t)blockIdx.z * obs;
  int r0 = blockIdx.y * 32, c0 = blockIdx.x * 32;
  int x = threadIdx.x, y = threadIdx.y;
  for (int i = y; i < 32; i += 8) t[i][x] = ip[(size_t)(r0 + i) * C + c0 + x];
  __syncthreads();
  for (int i = y; i < 32; i += 8) op[(size_t)(c0 + i) * R + r0 + x] = f2bf(t[x][i]);
}

// ------------- row softmax with mask, bf16 in-place (dense stride 2048) -------------
__global__ __launch_bounds__(256) void softmax_k(u16* __restrict__ P,
                                                 const int* __restrict__ mask,
                                                 float scale) {
  __shared__ float redm[4], reds[4];
  const int row = blockIdx.x;
  const int bb = row >> 11;
  const int tid = threadIdx.x;
  u16* p = P + (size_t)row * 2048;
  const int* mk = mask + (size_t)bb * 2048;
  uint4 raw = reinterpret_cast<const uint4*>(p)[tid];
  int4 ma = reinterpret_cast<const int4*>(mk)[2 * tid];
  int4 mc = reinterpret_cast<const int4*>(mk)[2 * tid + 1];
  float v[8];
  v[0] = ma.x ? bf2f((u16)(raw.x & 0xffff)) * scale : -1e30f;
  v[1] = ma.y ? bf2f((u16)(raw.x >> 16))    * scale : -1e30f;
  v[2] = ma.z ? bf2f((u16)(raw.y & 0xffff)) * scale : -1e30f;
  v[3] = ma.w ? bf2f((u16)(raw.y >> 16))    * scale : -1e30f;
  v[4] = mc.x ? bf2f((u16)(raw.z & 0xffff)) * scale : -1e30f;
  v[5] = mc.y ? bf2f((u16)(raw.z >> 16))    * scale : -1e30f;
  v[6] = mc.z ? bf2f((u16)(raw.w & 0xffff)) * scale : -1e30f;
  v[7] = mc.w ? bf2f((u16)(raw.w >> 16))    * scale : -1e30f;
  float mx = v[0];
  #pragma unroll
  for (int i = 1; i < 8; ++i) mx = fmaxf(mx, v[i]);
  for (int off = 32; off; off >>= 1) mx = fmaxf(mx, __shfl_xor(mx, off));
  if ((tid & 63) == 0) redm[tid >> 6] = mx;
  __syncthreads();
  mx = fmaxf(fmaxf(redm[0], redm[1]), fmaxf(redm[2], redm[3]));
  float sum = 0.f;
  #pragma unroll
  for (int i = 0; i < 8; ++i) { v[i] = __expf(v[i] - mx); sum += v[i]; }
  for (int off = 32; off; off >>= 1) sum += __shfl_xor(sum, off);
  if ((tid & 63) == 0) reds[tid >> 6] = sum;
  __syncthreads();
  sum = reds[0] + reds[1] + reds[2] + reds[3];
  float inv = 1.0f / sum;
  union { u16 u[8]; uint4 q; } r;
  #pragma unroll
  for (int i = 0; i < 8; ++i) r.u[i] = f2bf(v[i] * inv);
  reinterpret_cast<uint4*>(p)[tid] = r.q;
}

// ======== 128x64 / BK=64 dbuf counted-vmcnt GEMM, 48KB LDS -> 3 blocks/CU ========
// A:[*,K](LDA) bf16, K-split A/A2 at KSPLIT. Bt:[N,K](LDB), M-split at MSPLIT.
// 1-D grid NWG (mult of 8), XCD-chunked. EPI 0: relu->bf16 Cb | 1: bf16 Cb |
// 3: gate -> f32 Cf (R0 f32 cols<512, R1 bf16 cols>=512).
template <int EPI, int NT, int NX, int NY,
          int LDA, int LDB, int LDC, int KSPLIT, int MSPLIT,
          long long ABS, long long BBS, long long CBS, int NWG>
__global__ __launch_bounds__(256, 3) void gdb64(
    const u16* __restrict__ A, const u16* __restrict__ A2,
    const u16* __restrict__ Bt, const u16* __restrict__ Bt2,
    float* __restrict__ Cf, u16* __restrict__ Cb,
    const float* __restrict__ R0, const u16* __restrict__ R1) {
  __shared__ u16 As[2][128 * 64];   // 32 KB
  __shared__ u16 Bs[2][64 * 64];    // 16 KB
  const int bid = blockIdx.x;
  const int wgid = (bid & 7) * (NWG / 8) + (bid >> 3);
  const int bx = wgid % NX;
  const int by = (wgid / NX) % NY;
  const int bz = wgid / (NX * NY);
  const int tid = threadIdx.x;
  const int wave = tid >> 6, lane = tid & 63;
  const int m0 = by * 128, n0 = bx * 64;
  const int wr = wave >> 1, wc = wave & 1;               // each wave: 64x32 of C
  const int l15 = lane & 15, l4 = lane >> 4;
  const int srow = lane >> 3;
  const int scolsw = (((lane & 7) ^ (lane >> 3)) << 3);  // T2 pre-swizzled src col
  const int rsw = (l15 & 7) << 3;                        // read-side XOR
  const u16* Bbase = ((m0 < MSPLIT) ? Bt : Bt2) + (size_t)bz * BBS;
  const u16* Abase0 = A + (size_t)bz * ABS;
  const u16* Abase1 = A2 + (size_t)bz * ABS;

  f32x4 acc[4][2];
  #pragma unroll
  for (int i = 0; i < 4; ++i)
    #pragma unroll
    for (int j = 0; j < 2; ++j) acc[i][j] = (f32x4){0.f, 0.f, 0.f, 0.f};

  auto stage = [&](int buf, int k0) {                    // 6 gloads/thread
    const u16* Ab;
    int kl;
    if (k0 < KSPLIT) { Ab = Abase0; kl = k0; }
    else             { Ab = Abase1; kl = k0 - KSPLIT; }
    #pragma unroll
    for (int c = 0; c < 4; ++c) {
      int chunk = wave * 4 + c;                          // 0..15, 8 rows each
      int row = chunk * 8 + srow;
      gload16(Ab + (size_t)(m0 + row) * LDA + kl + scolsw, &As[buf][chunk * 512]);
    }
    #pragma unroll
    for (int c = 0; c < 2; ++c) {
      int chunk = wave * 2 + c;                          // 0..7, 8 rows each
      int row = chunk * 8 + srow;
      gload16(Bbase + (size_t)(n0 + row) * LDB + k0 + scolsw, &Bs[buf][chunk * 512]);
    }
  };
  auto compute = [&](int cur) {
    __builtin_amdgcn_s_setprio(1);
    #pragma unroll
    for (int kk = 0; kk < 64; kk += 32) {
      s16x8 af[4], bfr[2];
      #pragma unroll
      for (int mi = 0; mi < 4; ++mi)
        af[mi] = *reinterpret_cast<const s16x8*>(
            &As[cur][(wr * 64 + mi * 16 + l15) * 64 + ((kk + l4 * 8) ^ rsw)]);
      #pragma unroll
      for (int ni = 0; ni < 2; ++ni)
        bfr[ni] = *reinterpret_cast<const s16x8*>(
            &Bs[cur][(wc * 32 + ni * 16 + l15) * 64 + ((kk + l4 * 8) ^ rsw)]);
      #pragma unroll
      for (int mi = 0; mi < 4; ++mi)
        #pragma unroll
        for (int ni = 0; ni < 2; ++ni)
          acc[mi][ni] = mfma16(af[mi], bfr[ni], acc[mi][ni]);
    }
    __builtin_amdgcn_s_setprio(0);
  };

  stage(0, 0);
  stage(1, 64);
  WAITVM6();
  BAR();
  for (int t = 0; t < NT; ++t) {
    const int cur = t & 1;
    compute(cur);
    BAR();                                   // WAR: buf[cur] free
    if (t + 2 < NT) stage(cur, (t + 2) * 64);
    if (t + 1 < NT) {
      if (t + 2 < NT) { WAITVM6(); } else { WAITVM0(); }
      BAR();                                 // RAW: tile t+1 resident
    }
  }

  // ---- epilogue: 4 chunks of 32 rows x 64 cols f32 through LDS ----
  float* LF = (float*)(&As[0][0]);           // [32][68] f32 = 8.7 KB
  const int er = tid >> 3;                   // 0..31
  const int ec = (tid & 7) * 8;              // 8 f32/thread
  #pragma unroll
  for (int mi = 0; mi < 4; ++mi) {
    __syncthreads();
    #pragma unroll
    for (int ni = 0; ni < 2; ++ni) {
      int lc = wc * 32 + ni * 16 + l15;
      #pragma unroll
      for (int j = 0; j < 4; ++j)
        LF[(wr * 16 + l4 * 4 + j) * 68 + lc] = acc[mi][ni][j];
    }
    __syncthreads();
    int grow = m0 + (er >> 4) * 64 + mi * 16 + (er & 15);
    int gcol = n0 + ec;
    float v[8];
    #pragma unroll
    for (int i = 0; i < 2; ++i)
      *reinterpret_cast<f32x4*>(&v[4 * i]) =
          *reinterpret_cast<const f32x4*>(&LF[er * 68 + ec + 4 * i]);
    if (EPI == 3) {
      float* o = Cf + (size_t)bz * CBS + (size_t)grow * LDC + gcol;
      if (n0 < 512) {
        const float* r0 = R0 + (size_t)grow * 512 + gcol;
        #pragma unroll
        for (int i = 0; i < 8; ++i) {
          float g = 1.0f / (1.0f + __expf(-v[i]));
          v[i] = r0[i] * g;
        }
      } else {
        const u16* r1 = R1 + (size_t)grow * 512 + (gcol - 512);
        #pragma unroll
        for (int i = 0; i < 8; ++i) {
          float g = 1.0f / (1.0f + __expf(-v[i]));
          v[i] = bf2f(r1[i]) * g;
        }
      }
      reinterpret_cast<float4*>(o)[0] = *reinterpret_cast<float4*>(&v[0]);
      reinterpret_cast<float4*>(o)[1] = *reinterpret_cast<float4*>(&v[4]);
    } else {
      union { u16 u[8]; uint4 q; } pk;
      #pragma unroll
      for (int i = 0; i < 8; ++i)
        pk.u[i] = f2bf(EPI == 0 ? fmaxf(v[i], 0.f) : v[i]);
      u16* o = Cb + (size_t)bz * CBS + (size_t)grow * LDC + gcol;
      reinterpret_cast<uint4*>(o)[0] = pk.q;
    }
  }
}

// ======== P @ memory, 128x128 dbuf counted-vmcnt (control, frozen) ========
template <int EPI, int NT, int NX, int NY,
          int LDA, int LDB, int LDC, int KSPLIT, int MSPLIT,
          long long ABS, long long BBS, long long CBS, int NWG>
__global__ __launch_bounds__(256, 2) void gdb(
    const u16* __restrict__ A, const u16* __restrict__ A2,
    const u16* __restrict__ Bt, const u16* __restrict__ Bt2,
    float* __restrict__ Cf, u16* __restrict__ Cb,
    const float* __restrict__ R0, const u16* __restrict__ R1) {
  __shared__ u16 As[2][128 * 64];
  __shared__ u16 Bs[2][128 * 64];
  const int bid = blockIdx.x;
  const int wgid = (bid & 7) * (NWG / 8) + (bid >> 3);
  const int bx = wgid % NX;
  const int by = (wgid / NX) % NY;
  const int bz = wgid / (NX * NY);
  const int tid = threadIdx.x;
  const int wave = tid >> 6, lane = tid & 63;
  const int m0 = by * 128, n0 = bx * 128;
  const int wr = wave >> 1, wc = wave & 1;
  const int l15 = lane & 15, l4 = lane >> 4;
  const int srow = lane >> 3;
  const int scolsw = (((lane & 7) ^ (lane >> 3)) << 3);
  const int rsw = (l15 & 7) << 3;
  const u16* Bbase = ((m0 < MSPLIT) ? Bt : Bt2) + (size_t)bz * BBS;
  const u16* Abase0 = A + (size_t)bz * ABS;
  const u16* Abase1 = A2 + (size_t)bz * ABS;

  f32x4 acc[4][4];
  #pragma unroll
  for (int i = 0; i < 4; ++i)
    #pragma unroll
    for (int j = 0; j < 4; ++j) acc[i][j] = (f32x4){0.f, 0.f, 0.f, 0.f};

  auto stage = [&](int buf, int k0) {
    const u16* Ab;
    int kl;
    if (k0 < KSPLIT) { Ab = Abase0; kl = k0; }
    else             { Ab = Abase1; kl = k0 - KSPLIT; }
    #pragma unroll
    for (int c = 0; c < 4; ++c) {
      int chunk = wave * 4 + c;
      int row = chunk * 8 + srow;
      gload16(Ab + (size_t)(m0 + row) * LDA + kl + scolsw, &As[buf][chunk * 512]);
      gload16(Bbase + (size_t)(n0 + row) * LDB + k0 + scolsw, &Bs[buf][chunk * 512]);
    }
  };
  auto compute = [&](int cur) {
    __builtin_amdgcn_s_setprio(1);
    #pragma unroll
    for (int kk = 0; kk < 64; kk += 32) {
      s16x8 af[4], bfr[4];
      #pragma unroll
      for (int mi = 0; mi < 4; ++mi)
        af[mi] = *reinterpret_cast<const s16x8*>(
            &As[cur][(wr * 64 + mi * 16 + l15) * 64 + ((kk + l4 * 8) ^ rsw)]);
      #pragma unroll
      for (int ni = 0; ni < 4; ++ni)
        bfr[ni] = *reinterpret_cast<const s16x8*>(
            &Bs[cur][(wc * 64 + ni * 16 + l15) * 64 + ((kk + l4 * 8) ^ rsw)]);
      #pragma unroll
      for (int mi = 0; mi < 4; ++mi)
        #pragma unroll
        for (int ni = 0; ni < 4; ++ni)
          acc[mi][ni] = mfma16(af[mi], bfr[ni], acc[mi][ni]);
    }
    __builtin_amdgcn_s_setprio(0);
  };

  stage(0, 0);
  stage(1, 64);
  WAITVM8();
  BAR();
  for (int t = 0; t < NT; ++t) {
    const int cur = t & 1;
    compute(cur);
    BAR();
    if (t + 2 < NT) stage(cur, (t + 2) * 64);
    if (t + 1 < NT) {
      if (t + 2 < NT) { WAITVM8(); } else { WAITVM0(); }
      BAR();
    }
  }

  float* LF = (float*)(&As[0][0]);
  const int er = tid >> 3;
  const int ec = (tid & 7) * 16;
  #pragma unroll
  for (int mi = 0; mi < 4; ++mi) {
    __syncthreads();
    #pragma unroll
    for (int ni = 0; ni < 4; ++ni) {
      int lcol = wc * 64 + ni * 16 + l15;
      #pragma unroll
      for (int j = 0; j < 4; ++j)
        LF[(wr * 16 + l4 * 4 + j) * 132 + lcol] = acc[mi][ni][j];
    }
    __syncthreads();
    int grow = m0 + mi * 16 + (er & 15) + (er >> 4) * 64;
    int gcol = n0 + ec;
    float v[16];
    #pragma unroll
    for (int i = 0; i < 4; ++i)
      *reinterpret_cast<f32x4*>(&v[4 * i]) =
          *reinterpret_cast<const f32x4*>(&LF[er * 132 + ec + 4 * i]);
    union { u16 u[16]; uint4 q[2]; } pk;
    #pragma unroll
    for (int i = 0; i < 16; ++i)
      pk.u[i] = f2bf(EPI == 0 ? fmaxf(v[i], 0.f) : v[i]);
    u16* o = Cb + (size_t)bz * CBS + (size_t)grow * LDC + gcol;
    reinterpret_cast<uint4*>(o)[0] = pk.q[0];
    reinterpret_cast<uint4*>(o)[1] = pk.q[1];
  }
  (void)Cf; (void)R0; (void)R1;
}

extern "C" void kernel_launch(void* const* d_in, const int* in_sizes, int n_in,
                              void* d_out, int out_size, void* d_ws, size_t ws_size,
                              hipStream_t stream) {
  const float* inputs = (const float*)d_in[0];  // [8,2048,512]
  const float* memory = (const float*)d_in[1];  // [8,2048,512]
  const int*   mask   = (const int*)d_in[2];    // [8,2048]
  const float* Wq     = (const float*)d_in[3];  // [512,512]
  const float* Wk     = (const float*)d_in[4];  // [512,512]
  const float* Wg     = (const float*)d_in[5];  // [1024,1024]
  float* out = (float*)d_out;                   // [8,2048,1024]

  char* ws = (char*)d_ws;
  size_t off = 0;
  auto alloc = [&](size_t bytes) {
    void* p = ws + off;
    off += (bytes + 255) & ~(size_t)255;
    return p;
  };
  u16* in_b  = (u16*)alloc(16384ULL * 512 * 2);   // } contiguous pair [inputs|memory]
  u16* mem_b = (u16*)alloc(16384ULL * 512 * 2);   // }
  u16* memT  = (u16*)alloc(16384ULL * 512 * 2);   // memory^T bf16 [B][512][2048]
  u16* WqT   = (u16*)alloc(512ULL * 512 * 2);
  u16* WkT   = (u16*)alloc(512ULL * 512 * 2);
  u16* WgT   = (u16*)alloc(1024ULL * 1024 * 2);
  u16* q_b   = (u16*)alloc(16384ULL * 512 * 2);   // } contiguous pair [q|k]
  u16* k_b   = (u16*)alloc(16384ULL * 512 * 2);   // }
  u16* sc    = (u16*)alloc(8ULL * 2048 * 2048 * 2);  // scores/P bf16 dense
  u16* att_b = (u16*)alloc(16384ULL * 512 * 2);
  (void)ws_size; (void)in_sizes; (void)n_in; (void)out_size;

  const int n8 = (16384 * 512) / 8;
  cvt_k<<<(n8 + 255) / 256, 256, 0, stream>>>(inputs, in_b, n8);
  // memory: single read -> bf16 copy (mem_b) + transpose (memT)
  cvtT_k<<<dim3(16, 64, 8), dim3(32, 8), 0, stream>>>(memory, mem_b, memT);
  dim3 tb(32, 8);
  tcvt_k<<<dim3(16, 16, 1), tb, 0, stream>>>(Wq, WqT, 512, 512, 0, 0);
  tcvt_k<<<dim3(16, 16, 1), tb, 0, stream>>>(Wk, WkT, 512, 512, 0, 0);
  tcvt_k<<<dim3(32, 32, 1), tb, 0, stream>>>(Wg, WgT, 1024, 1024, 0, 0);

  const int BIG = 1 << 30;
  (void)BIG;

  // [q|k] = relu([inputs|memory] @ [Wq or Wk])  M=32768 N=512 K=512
  gdb64<0, 8, 8, 256, 512, 512, 512, (1 << 30), 16384, 0, 0, 0, 2048>
      <<<2048, 256, 0, stream>>>(in_b, in_b, WqT, WkT, nullptr, q_b,
                                 nullptr, nullptr);

  // scores[b] = q[b] @ k[b]^T -> bf16 dense [2048][2048]
  gdb64<1, 8, 32, 16, 512, 512, 2048, (1 << 30), (1 << 30),
        2048LL * 512, 2048LL * 512, 2048LL * 2048, 4096>
      <<<4096, 256, 0, stream>>>(q_b, q_b, k_b, k_b, nullptr, sc,
                                 nullptr, nullptr);

  // masked scaled softmax, bf16 in place (dense)
  softmax_k<<<16384, 256, 0, stream>>>(sc, mask, 0.044194173824159216f);

  // att[b] = P[b] @ memory[b] -> bf16  (M=2048 N=512 K=2048 per batch)
  gdb<1, 32, 4, 16, 2048, 2048, 512, (1 << 30), (1 << 30),
      2048LL * 2048, 512LL * 2048, 2048LL * 512, 512>
      <<<512, 256, 0, stream>>>(sc, sc, memT, memT, nullptr, att_b,
                                nullptr, nullptr);

  // out = res * sigmoid(res @ Wg), res = [inputs | att]; A K-split at 512
  gdb64<3, 16, 16, 128, 512, 1024, 1024, 512, (1 << 30), 0, 0, 0, 2048>
      <<<2048, 256, 0, stream>>>(in_b, att_b, WgT, WgT, out, nullptr,
                                 inputs, att_b);
}

// Round 11
// 231.175 us; speedup vs baseline: 1.0671x; 1.0151x over previous
//
#include <hip/hip_runtime.h>

typedef unsigned short u16;
typedef unsigned int   u32;

typedef short s16x8 __attribute__((ext_vector_type(8)));
typedef float f32x4 __attribute__((ext_vector_type(4)));

static __device__ __forceinline__ u16 f2bf(float f) {
  u32 u = __float_as_uint(f);
  u = (u + 0x7fffu + ((u >> 16) & 1u)) >> 16;
  return (u16)u;
}
static __device__ __forceinline__ float bf2f(u16 h) {
  return __uint_as_float(((u32)h) << 16);
}
static __device__ __forceinline__ f32x4 mfma16(s16x8 a, s16x8 b, f32x4 c) {
  return __builtin_amdgcn_mfma_f32_16x16x32_bf16(a, b, c, 0, 0, 0);
}
static __device__ __forceinline__ void gload16(const u16* g, u16* l) {
  __builtin_amdgcn_global_load_lds(
      (const __attribute__((address_space(1))) void*)g,
      (__attribute__((address_space(3))) void*)l, 16, 0, 0);
}

#define WAITVM8() asm volatile("s_waitcnt vmcnt(8)" ::: "memory")
#define WAITVM6() asm volatile("s_waitcnt vmcnt(6)" ::: "memory")
#define WAITVM0() asm volatile("s_waitcnt vmcnt(0)" ::: "memory")
#define BAR()                                  \
  do {                                         \
    asm volatile("" ::: "memory");             \
    __builtin_amdgcn_s_barrier();              \
    asm volatile("" ::: "memory");             \
  } while (0)

// ---------------- flat f32 -> bf16 convert, 8 elems/thread ----------------
__global__ __launch_bounds__(256) void cvt_k(const float* __restrict__ in,
                                             u16* __restrict__ out, int n8) {
  int i = blockIdx.x * 256 + threadIdx.x;
  if (i >= n8) return;
  const float4* p = reinterpret_cast<const float4*>(in);
  float4 a = p[2 * i], b = p[2 * i + 1];
  union { u16 u[8]; uint4 v; } r;
  r.u[0] = f2bf(a.x); r.u[1] = f2bf(a.y); r.u[2] = f2bf(a.z); r.u[3] = f2bf(a.w);
  r.u[4] = f2bf(b.x); r.u[5] = f2bf(b.y); r.u[6] = f2bf(b.z); r.u[7] = f2bf(b.w);
  reinterpret_cast<uint4*>(out)[i] = r.v;
}

// ------- memory: one read -> bf16 row-major copy AND bf16 transpose -------
__global__ void cvtT_k(const float* __restrict__ in, u16* __restrict__ rm,
                       u16* __restrict__ tr) {
  __shared__ float t[32][33];
  const int z = blockIdx.z;
  const float* ip = in + (size_t)z * 2048 * 512;
  int r0 = blockIdx.y * 32, c0 = blockIdx.x * 32;
  int x = threadIdx.x, y = threadIdx.y;
  for (int i = y; i < 32; i += 8) t[i][x] = ip[(size_t)(r0 + i) * 512 + c0 + x];
  __syncthreads();
  u16* rp = rm + (size_t)z * 2048 * 512;
  u16* tp = tr + (size_t)z * 512 * 2048;
  for (int i = y; i < 32; i += 8) rp[(size_t)(r0 + i) * 512 + c0 + x] = f2bf(t[i][x]);
  for (int i = y; i < 32; i += 8) tp[(size_t)(c0 + i) * 2048 + r0 + x] = f2bf(t[x][i]);
}

// ------------- transpose+convert: in [R,C] f32 -> out [C,R] bf16 -------------
__global__ void tcvt_k(const float* __restrict__ in, u16* __restrict__ out,
                       int R, int C, long long ibs, long long obs) {
  __shared__ float t[32][33];
  const float* ip = in + (size_t)blockIdx.z * ibs;
  u16* op = out + (size_t)blockIdx.z * obs;
  int r0 = blockIdx.y * 32, c0 = blockIdx.x * 32;
  int x = threadIdx.x, y = threadIdx.y;
  for (int i = y; i < 32; i += 8) t[i][x] = ip[(size_t)(r0 + i) * C + c0 + x];
  __syncthreads();
  for (int i = y; i < 32; i += 8) op[(size_t)(c0 + i) * R + r0 + x] = f2bf(t[x][i]);
}

// ------------- row softmax with mask, bf16 in-place (dense stride 2048) -------------
__global__ __launch_bounds__(256) void softmax_k(u16* __restrict__ P,
                                                 const int* __restrict__ mask,
                                                 float scale) {
  __shared__ float redm[4], reds[4];
  const int row = blockIdx.x;
  const int bb = row >> 11;
  const int tid = threadIdx.x;
  u16* p = P + (size_t)row * 2048;
  const int* mk = mask + (size_t)bb * 2048;
  uint4 raw = reinterpret_cast<const uint4*>(p)[tid];
  int4 ma = reinterpret_cast<const int4*>(mk)[2 * tid];
  int4 mc = reinterpret_cast<const int4*>(mk)[2 * tid + 1];
  float v[8];
  v[0] = ma.x ? bf2f((u16)(raw.x & 0xffff)) * scale : -1e30f;
  v[1] = ma.y ? bf2f((u16)(raw.x >> 16))    * scale : -1e30f;
  v[2] = ma.z ? bf2f((u16)(raw.y & 0xffff)) * scale : -1e30f;
  v[3] = ma.w ? bf2f((u16)(raw.y >> 16))    * scale : -1e30f;
  v[4] = mc.x ? bf2f((u16)(raw.z & 0xffff)) * scale : -1e30f;
  v[5] = mc.y ? bf2f((u16)(raw.z >> 16))    * scale : -1e30f;
  v[6] = mc.z ? bf2f((u16)(raw.w & 0xffff)) * scale : -1e30f;
  v[7] = mc.w ? bf2f((u16)(raw.w >> 16))    * scale : -1e30f;
  float mx = v[0];
  #pragma unroll
  for (int i = 1; i < 8; ++i) mx = fmaxf(mx, v[i]);
  for (int off = 32; off; off >>= 1) mx = fmaxf(mx, __shfl_xor(mx, off));
  if ((tid & 63) == 0) redm[tid >> 6] = mx;
  __syncthreads();
  mx = fmaxf(fmaxf(redm[0], redm[1]), fmaxf(redm[2], redm[3]));
  float sum = 0.f;
  #pragma unroll
  for (int i = 0; i < 8; ++i) { v[i] = __expf(v[i] - mx); sum += v[i]; }
  for (int off = 32; off; off >>= 1) sum += __shfl_xor(sum, off);
  if ((tid & 63) == 0) reds[tid >> 6] = sum;
  __syncthreads();
  sum = reds[0] + reds[1] + reds[2] + reds[3];
  float inv = 1.0f / sum;
  union { u16 u[8]; uint4 q; } r;
  #pragma unroll
  for (int i = 0; i < 8; ++i) r.u[i] = f2bf(v[i] * inv);
  reinterpret_cast<uint4*>(p)[tid] = r.q;
}

// ======== 128x128 / BK=64 dbuf counted-vmcnt GEMM (best-known family) ========
// EPI 0: relu->bf16 Cb | 1: bf16 Cb
template <int EPI, int NT, int NX, int NY,
          int LDA, int LDB, int LDC, int KSPLIT, int MSPLIT,
          long long ABS, long long BBS, long long CBS, int NWG>
__global__ __launch_bounds__(256, 2) void gdb(
    const u16* __restrict__ A, const u16* __restrict__ A2,
    const u16* __restrict__ Bt, const u16* __restrict__ Bt2,
    float* __restrict__ Cf, u16* __restrict__ Cb,
    const u16* __restrict__ R0, const u16* __restrict__ R1) {
  __shared__ u16 As[2][128 * 64];
  __shared__ u16 Bs[2][128 * 64];
  const int bid = blockIdx.x;
  const int wgid = (bid & 7) * (NWG / 8) + (bid >> 3);
  const int bx = wgid % NX;
  const int by = (wgid / NX) % NY;
  const int bz = wgid / (NX * NY);
  const int tid = threadIdx.x;
  const int wave = tid >> 6, lane = tid & 63;
  const int m0 = by * 128, n0 = bx * 128;
  const int wr = wave >> 1, wc = wave & 1;
  const int l15 = lane & 15, l4 = lane >> 4;
  const int srow = lane >> 3;
  const int scolsw = (((lane & 7) ^ (lane >> 3)) << 3);
  const int rsw = (l15 & 7) << 3;
  const u16* Bbase = ((m0 < MSPLIT) ? Bt : Bt2) + (size_t)bz * BBS;
  const u16* Abase0 = A + (size_t)bz * ABS;
  const u16* Abase1 = A2 + (size_t)bz * ABS;

  f32x4 acc[4][4];
  #pragma unroll
  for (int i = 0; i < 4; ++i)
    #pragma unroll
    for (int j = 0; j < 4; ++j) acc[i][j] = (f32x4){0.f, 0.f, 0.f, 0.f};

  auto stage = [&](int buf, int k0) {
    const u16* Ab;
    int kl;
    if (k0 < KSPLIT) { Ab = Abase0; kl = k0; }
    else             { Ab = Abase1; kl = k0 - KSPLIT; }
    #pragma unroll
    for (int c = 0; c < 4; ++c) {
      int chunk = wave * 4 + c;
      int row = chunk * 8 + srow;
      gload16(Ab + (size_t)(m0 + row) * LDA + kl + scolsw, &As[buf][chunk * 512]);
      gload16(Bbase + (size_t)(n0 + row) * LDB + k0 + scolsw, &Bs[buf][chunk * 512]);
    }
  };
  auto compute = [&](int cur) {
    __builtin_amdgcn_s_setprio(1);
    #pragma unroll
    for (int kk = 0; kk < 64; kk += 32) {
      s16x8 af[4], bfr[4];
      #pragma unroll
      for (int mi = 0; mi < 4; ++mi)
        af[mi] = *reinterpret_cast<const s16x8*>(
            &As[cur][(wr * 64 + mi * 16 + l15) * 64 + ((kk + l4 * 8) ^ rsw)]);
      #pragma unroll
      for (int ni = 0; ni < 4; ++ni)
        bfr[ni] = *reinterpret_cast<const s16x8*>(
            &Bs[cur][(wc * 64 + ni * 16 + l15) * 64 + ((kk + l4 * 8) ^ rsw)]);
      #pragma unroll
      for (int mi = 0; mi < 4; ++mi)
        #pragma unroll
        for (int ni = 0; ni < 4; ++ni)
          acc[mi][ni] = mfma16(af[mi], bfr[ni], acc[mi][ni]);
    }
    __builtin_amdgcn_s_setprio(0);
  };

  stage(0, 0);
  stage(1, 64);
  WAITVM8();
  BAR();
  for (int t = 0; t < NT; ++t) {
    const int cur = t & 1;
    compute(cur);
    BAR();
    if (t + 2 < NT) stage(cur, (t + 2) * 64);
    if (t + 1 < NT) {
      if (t + 2 < NT) { WAITVM8(); } else { WAITVM0(); }
      BAR();
    }
  }

  float* LF = (float*)(&As[0][0]);
  const int er = tid >> 3;
  const int ec = (tid & 7) * 16;
  #pragma unroll
  for (int mi = 0; mi < 4; ++mi) {
    __syncthreads();
    #pragma unroll
    for (int ni = 0; ni < 4; ++ni) {
      int lcol = wc * 64 + ni * 16 + l15;
      #pragma unroll
      for (int j = 0; j < 4; ++j)
        LF[(wr * 16 + l4 * 4 + j) * 132 + lcol] = acc[mi][ni][j];
    }
    __syncthreads();
    int grow = m0 + mi * 16 + (er & 15) + (er >> 4) * 64;
    int gcol = n0 + ec;
    float v[16];
    #pragma unroll
    for (int i = 0; i < 4; ++i)
      *reinterpret_cast<f32x4*>(&v[4 * i]) =
          *reinterpret_cast<const f32x4*>(&LF[er * 132 + ec + 4 * i]);
    union { u16 u[16]; uint4 q[2]; } pk;
    #pragma unroll
    for (int i = 0; i < 16; ++i)
      pk.u[i] = f2bf(EPI == 0 ? fmaxf(v[i], 0.f) : v[i]);
    u16* o = Cb + (size_t)bz * CBS + (size_t)grow * LDC + gcol;
    reinterpret_cast<uint4*>(o)[0] = pk.q[0];
    reinterpret_cast<uint4*>(o)[1] = pk.q[1];
  }
  (void)Cf; (void)R0; (void)R1;
}

// ======== 128x64 / BK=64 dbuf counted-vmcnt, 48KB LDS -> 3 blocks/CU ========
// EPI 0: relu->bf16 Cb | 3: gate -> f32 Cf (R0 bf16 cols<512, R1 bf16 cols>=512)
template <int EPI, int NT, int NX, int NY,
          int LDA, int LDB, int LDC, int KSPLIT, int MSPLIT,
          long long ABS, long long BBS, long long CBS, int NWG>
__global__ __launch_bounds__(256, 3) void gdb64(
    const u16* __restrict__ A, const u16* __restrict__ A2,
    const u16* __restrict__ Bt, const u16* __restrict__ Bt2,
    float* __restrict__ Cf, u16* __restrict__ Cb,
    const u16* __restrict__ R0, const u16* __restrict__ R1) {
  __shared__ u16 As[2][128 * 64];   // 32 KB
  __shared__ u16 Bs[2][64 * 64];    // 16 KB
  const int bid = blockIdx.x;
  const int wgid = (bid & 7) * (NWG / 8) + (bid >> 3);
  const int bx = wgid % NX;
  const int by = (wgid / NX) % NY;
  const int bz = wgid / (NX * NY);
  const int tid = threadIdx.x;
  const int wave = tid >> 6, lane = tid & 63;
  const int m0 = by * 128, n0 = bx * 64;
  const int wr = wave >> 1, wc = wave & 1;               // each wave: 64x32 of C
  const int l15 = lane & 15, l4 = lane >> 4;
  const int srow = lane >> 3;
  const int scolsw = (((lane & 7) ^ (lane >> 3)) << 3);
  const int rsw = (l15 & 7) << 3;
  const u16* Bbase = ((m0 < MSPLIT) ? Bt : Bt2) + (size_t)bz * BBS;
  const u16* Abase0 = A + (size_t)bz * ABS;
  const u16* Abase1 = A2 + (size_t)bz * ABS;

  f32x4 acc[4][2];
  #pragma unroll
  for (int i = 0; i < 4; ++i)
    #pragma unroll
    for (int j = 0; j < 2; ++j) acc[i][j] = (f32x4){0.f, 0.f, 0.f, 0.f};

  auto stage = [&](int buf, int k0) {                    // 6 gloads/thread
    const u16* Ab;
    int kl;
    if (k0 < KSPLIT) { Ab = Abase0; kl = k0; }
    else             { Ab = Abase1; kl = k0 - KSPLIT; }
    #pragma unroll
    for (int c = 0; c < 4; ++c) {
      int chunk = wave * 4 + c;
      int row = chunk * 8 + srow;
      gload16(Ab + (size_t)(m0 + row) * LDA + kl + scolsw, &As[buf][chunk * 512]);
    }
    #pragma unroll
    for (int c = 0; c < 2; ++c) {
      int chunk = wave * 2 + c;
      int row = chunk * 8 + srow;
      gload16(Bbase + (size_t)(n0 + row) * LDB + k0 + scolsw, &Bs[buf][chunk * 512]);
    }
  };
  auto compute = [&](int cur) {
    __builtin_amdgcn_s_setprio(1);
    #pragma unroll
    for (int kk = 0; kk < 64; kk += 32) {
      s16x8 af[4], bfr[2];
      #pragma unroll
      for (int mi = 0; mi < 4; ++mi)
        af[mi] = *reinterpret_cast<const s16x8*>(
            &As[cur][(wr * 64 + mi * 16 + l15) * 64 + ((kk + l4 * 8) ^ rsw)]);
      #pragma unroll
      for (int ni = 0; ni < 2; ++ni)
        bfr[ni] = *reinterpret_cast<const s16x8*>(
            &Bs[cur][(wc * 32 + ni * 16 + l15) * 64 + ((kk + l4 * 8) ^ rsw)]);
      #pragma unroll
      for (int mi = 0; mi < 4; ++mi)
        #pragma unroll
        for (int ni = 0; ni < 2; ++ni)
          acc[mi][ni] = mfma16(af[mi], bfr[ni], acc[mi][ni]);
    }
    __builtin_amdgcn_s_setprio(0);
  };

  stage(0, 0);
  stage(1, 64);
  WAITVM6();
  BAR();
  for (int t = 0; t < NT; ++t) {
    const int cur = t & 1;
    compute(cur);
    BAR();
    if (t + 2 < NT) stage(cur, (t + 2) * 64);
    if (t + 1 < NT) {
      if (t + 2 < NT) { WAITVM6(); } else { WAITVM0(); }
      BAR();
    }
  }

  // ---- epilogue: 4 chunks of 32 rows x 64 cols f32 through LDS ----
  float* LF = (float*)(&As[0][0]);           // [32][68] f32
  const int er = tid >> 3;                   // 0..31
  const int ec = (tid & 7) * 8;              // 8 f32/thread
  #pragma unroll
  for (int mi = 0; mi < 4; ++mi) {
    __syncthreads();
    #pragma unroll
    for (int ni = 0; ni < 2; ++ni) {
      int lc = wc * 32 + ni * 16 + l15;
      #pragma unroll
      for (int j = 0; j < 4; ++j)
        LF[(wr * 16 + l4 * 4 + j) * 68 + lc] = acc[mi][ni][j];
    }
    __syncthreads();
    int grow = m0 + (er >> 4) * 64 + mi * 16 + (er & 15);
    int gcol = n0 + ec;
    float v[8];
    #pragma unroll
    for (int i = 0; i < 2; ++i)
      *reinterpret_cast<f32x4*>(&v[4 * i]) =
          *reinterpret_cast<const f32x4*>(&LF[er * 68 + ec + 4 * i]);
    if (EPI == 3) {
      float* o = Cf + (size_t)bz * CBS + (size_t)grow * LDC + gcol;
      const u16* rb = (n0 < 512) ? (R0 + (size_t)grow * 512 + gcol)
                                 : (R1 + (size_t)grow * 512 + (gcol - 512));
      #pragma unroll
      for (int i = 0; i < 8; ++i) {
        float g = 1.0f / (1.0f + __expf(-v[i]));
        v[i] = bf2f(rb[i]) * g;
      }
      reinterpret_cast<float4*>(o)[0] = *reinterpret_cast<float4*>(&v[0]);
      reinterpret_cast<float4*>(o)[1] = *reinterpret_cast<float4*>(&v[4]);
    } else {
      union { u16 u[8]; uint4 q; } pk;
      #pragma unroll
      for (int i = 0; i < 8; ++i)
        pk.u[i] = f2bf(EPI == 0 ? fmaxf(v[i], 0.f) : v[i]);
      u16* o = Cb + (size_t)bz * CBS + (size_t)grow * LDC + gcol;
      reinterpret_cast<uint4*>(o)[0] = pk.q;
    }
  }
}

extern "C" void kernel_launch(void* const* d_in, const int* in_sizes, int n_in,
                              void* d_out, int out_size, void* d_ws, size_t ws_size,
                              hipStream_t stream) {
  const float* inputs = (const float*)d_in[0];  // [8,2048,512]
  const float* memory = (const float*)d_in[1];  // [8,2048,512]
  const int*   mask   = (const int*)d_in[2];    // [8,2048]
  const float* Wq     = (const float*)d_in[3];  // [512,512]
  const float* Wk     = (const float*)d_in[4];  // [512,512]
  const float* Wg     = (const float*)d_in[5];  // [1024,1024]
  float* out = (float*)d_out;                   // [8,2048,1024]

  char* ws = (char*)d_ws;
  size_t off = 0;
  auto alloc = [&](size_t bytes) {
    void* p = ws + off;
    off += (bytes + 255) & ~(size_t)255;
    return p;
  };
  u16* in_b  = (u16*)alloc(16384ULL * 512 * 2);   // } contiguous pair [inputs|memory]
  u16* mem_b = (u16*)alloc(16384ULL * 512 * 2);   // }
  u16* memT  = (u16*)alloc(16384ULL * 512 * 2);   // memory^T bf16 [B][512][2048]
  u16* WqT   = (u16*)alloc(512ULL * 512 * 2);
  u16* WkT   = (u16*)alloc(512ULL * 512 * 2);
  u16* WgT   = (u16*)alloc(1024ULL * 1024 * 2);
  u16* q_b   = (u16*)alloc(16384ULL * 512 * 2);   // } contiguous pair [q|k]
  u16* k_b   = (u16*)alloc(16384ULL * 512 * 2);   // }
  u16* sc    = (u16*)alloc(8ULL * 2048 * 2048 * 2);  // scores/P bf16 dense
  u16* att_b = (u16*)alloc(16384ULL * 512 * 2);
  (void)ws_size; (void)in_sizes; (void)n_in; (void)out_size;

  const int n8 = (16384 * 512) / 8;
  cvt_k<<<(n8 + 255) / 256, 256, 0, stream>>>(inputs, in_b, n8);
  cvtT_k<<<dim3(16, 64, 8), dim3(32, 8), 0, stream>>>(memory, mem_b, memT);
  dim3 tb(32, 8);
  tcvt_k<<<dim3(16, 16, 1), tb, 0, stream>>>(Wq, WqT, 512, 512, 0, 0);
  tcvt_k<<<dim3(16, 16, 1), tb, 0, stream>>>(Wk, WkT, 512, 512, 0, 0);
  tcvt_k<<<dim3(32, 32, 1), tb, 0, stream>>>(Wg, WgT, 1024, 1024, 0, 0);

  // [q|k] = relu([inputs|memory] @ [Wq or Wk])  M=32768 N=512 K=512
  gdb64<0, 8, 8, 256, 512, 512, 512, (1 << 30), 16384, 0, 0, 0, 2048>
      <<<2048, 256, 0, stream>>>(in_b, in_b, WqT, WkT, nullptr, q_b,
                                 nullptr, nullptr);

  // scores[b] = q[b] @ k[b]^T -> bf16 dense [2048][2048]  (128x128 family)
  gdb<1, 8, 16, 16, 512, 512, 2048, (1 << 30), (1 << 30),
      2048LL * 512, 2048LL * 512, 2048LL * 2048, 2048>
      <<<2048, 256, 0, stream>>>(q_b, q_b, k_b, k_b, nullptr, sc,
                                 nullptr, nullptr);

  // masked scaled softmax, bf16 in place (dense)
  softmax_k<<<16384, 256, 0, stream>>>(sc, mask, 0.044194173824159216f);

  // att[b] = P[b] @ memory[b] -> bf16  (M=2048 N=512 K=2048 per batch)
  gdb<1, 32, 4, 16, 2048, 2048, 512, (1 << 30), (1 << 30),
      2048LL * 2048, 512LL * 2048, 2048LL * 512, 512>
      <<<512, 256, 0, stream>>>(sc, sc, memT, memT, nullptr, att_b,
                                nullptr, nullptr);

  // out = res * sigmoid(res @ Wg), res = [in_b(bf16) | att_b]; A K-split at 512
  gdb64<3, 16, 16, 128, 512, 1024, 1024, 512, (1 << 30), 0, 0, 0, 2048>
      <<<2048, 256, 0, stream>>>(in_b, att_b, WgT, WgT, out, nullptr,
                                 in_b, att_b);
}